// Round 1
// baseline (232.609 us; speedup 1.0000x reference)
//
#include <hip/hip_runtime.h>
#include <hip/hip_bf16.h>

// Problem constants
#define H_ 128
#define W_ 128
#define HW 16384          // H*W
#define CIN 64
#define COUT 128
#define KK9 9
#define BATCH 8
#define NPIX (BATCH * HW) // 131072
#define KDIM 576          // CIN*KK9

typedef short bf16x8 __attribute__((ext_vector_type(8)));
typedef float f32x4  __attribute__((ext_vector_type(4)));
typedef unsigned short ushort_t;

union U4B { uint4 u; bf16x8 v; };

__device__ __forceinline__ float us2f(unsigned short u) {
    unsigned int v = ((unsigned int)u) << 16;
    float f;
    __builtin_memcpy(&f, &v, 4);
    return f;
}
__device__ __forceinline__ float lo_f(unsigned int w) {
    unsigned int v = w << 16;
    float f;
    __builtin_memcpy(&f, &v, 4);
    return f;
}
__device__ __forceinline__ float hi_f(unsigned int w) {
    unsigned int v = w & 0xffff0000u;
    float f;
    __builtin_memcpy(&f, &v, 4);
    return f;
}
__device__ __forceinline__ unsigned short f2us_bf(float f) {
    __hip_bfloat16 h = __float2bfloat16(f);
    unsigned short u;
    __builtin_memcpy(&u, &h, 2);
    return u;
}
__device__ __forceinline__ unsigned int pack2(float a, float b) {
    return (unsigned int)f2us_bf(a) | ((unsigned int)f2us_bf(b) << 16);
}

template <bool F32>
__device__ __forceinline__ float ld_in(const void* p, long i) {
    if (F32) return ((const float*)p)[i];
    return us2f(((const unsigned short*)p)[i]);
}

// ---------------------------------------------------------------------------
// detect_zero: dtype probe (1 wave, vector loads, ballot) + zero gstat.
// ---------------------------------------------------------------------------
__global__ void detect_zero(const uint4* __restrict__ xr4,
                            float* __restrict__ flag,
                            float* __restrict__ gstat) {
    int t = threadIdx.x;   // 256
#pragma unroll
    for (int i = 0; i < 16; ++i) gstat[i * 256 + t] = 0.0f;
    if (t < 64) {
        uint4 v = xr4[t];
        unsigned int w[4] = {v.x, v.y, v.z, v.w};
        int big = 0;
#pragma unroll
        for (int q = 0; q < 4; ++q) {
            big += (((w[q] >> 7)  & 0xFF) >= 0xC0);
            big += (((w[q] >> 23) & 0xFF) >= 0xC0);
        }
        unsigned long long m = __ballot(big > 0);
        if (t == 0) flag[0] = m ? 1.0f : 0.0f;
    }
}

// ---------------------------------------------------------------------------
// prep_weights: weights in MFMA-fragment-linear order. Single kernel,
// internal wave-uniform branch on flag.
// ---------------------------------------------------------------------------
template <bool F32>
__device__ __forceinline__ void prep_body(const void* offw, const void* offb,
                                          const void* maskw, const void* maskb,
                                          const void* convw,
                                          ushort_t* wTs, ushort_t* wcats,
                                          float* bias, int i) {
    if (i < 73728) {
        int j = i & 7, lane = (i >> 3) & 63, n = (i >> 9) & 7, ks = i >> 12;
        int co = n * 16 + (lane & 15);
        int k  = ks * 32 + ((lane >> 4) << 3) + j;
        int kk = k >> 6, ci = k & 63;
        wTs[i] = f2us_bf(ld_in<F32>(convw, (long)co * KDIM + ci * 9 + kk));
    } else if (i < 73728 + 18432) {
        int i2 = i - 73728;
        int j = i2 & 7, lane = (i2 >> 3) & 63, n = (i2 >> 9) & 1, ks = i2 >> 10;
        int co2 = n * 16 + (lane & 15);
        int k   = ks * 32 + ((lane >> 4) << 3) + j;
        int kk = k >> 6, ci = k & 63;
        float v = 0.0f;
        if (co2 < 18)      v = ld_in<F32>(offw,  (long)co2 * KDIM + ci * 9 + kk);
        else if (co2 < 27) v = ld_in<F32>(maskw, (long)(co2 - 18) * KDIM + ci * 9 + kk);
        wcats[i2] = f2us_bf(v);
    } else if (i < 73728 + 18432 + 32) {
        int j = i - 73728 - 18432;
        float v = 0.0f;
        if (j < 18)      v = ld_in<F32>(offb, j);
        else if (j < 27) v = ld_in<F32>(maskb, j - 18);
        bias[j] = v;
    }
}

__global__ void prep_weights(const void* __restrict__ offw,
                             const void* __restrict__ offb,
                             const void* __restrict__ maskw,
                             const void* __restrict__ maskb,
                             const void* __restrict__ convw,
                             const float* __restrict__ flag,
                             ushort_t* __restrict__ wTs,
                             ushort_t* __restrict__ wcats,
                             float* __restrict__ bias) {
    int i = blockIdx.x * 256 + threadIdx.x;
    if (flag[0] != 0.0f)
        prep_body<true>(offw, offb, maskw, maskb, convw, wTs, wcats, bias, i);
    else
        prep_body<false>(offw, offb, maskw, maskb, convw, wTs, wcats, bias, i);
}

// ---------------------------------------------------------------------------
// transpose_x: raw x NCHW -> NHWC bf16. Single kernel, internal flag branch.
// ---------------------------------------------------------------------------
template <bool F32>
__device__ __forceinline__ void transpose_body(const void* x, ushort_t* xnb) {
    __shared__ float tile[CIN][64 + 1];
    int blk  = blockIdx.x;
    int b    = blk >> 8;
    int pix0 = (blk & 255) * 64;
    int t    = threadIdx.x;
    int lane = t & 63;
    int grp  = t >> 6;
#pragma unroll
    for (int r = 0; r < 16; ++r) {
        int ci = r * 4 + grp;
        tile[ci][lane] = ld_in<F32>(x, (long)(b * CIN + ci) * HW + pix0 + lane);
    }
    __syncthreads();
#pragma unroll
    for (int r = 0; r < 16; ++r) {
        int px = r * 4 + grp;
        xnb[(size_t)(b * HW + pix0 + px) * CIN + lane] = f2us_bf(tile[lane][px]);
    }
}

__global__ __launch_bounds__(256) void transpose_x(const void* __restrict__ x,
                                                   const float* __restrict__ flag,
                                                   ushort_t* __restrict__ xnb) {
    if (flag[0] != 0.0f) transpose_body<true>(x, xnb);
    else                 transpose_body<false>(x, xnb);
}

// ---------------------------------------------------------------------------
// conv_mfma: implicit-GEMM 3x3 conv -> 27 ch. 1024 thr / 256 px / 16 waves.
// ---------------------------------------------------------------------------
__global__ __launch_bounds__(1024, 4) void conv_mfma(
        const ushort_t* __restrict__ xnb,
        const ushort_t* __restrict__ wcats,
        const float* __restrict__ bias,
        float* __restrict__ off2,
        float* __restrict__ mask_ws) {
    __shared__ uint4 ldsB4[2304];    // 36,864 B

    int t    = threadIdx.x;
    int pix0 = blockIdx.x * 256;
    int b    = pix0 >> 14;
    int rem0 = pix0 & 16383;

    const uint4* ws4 = (const uint4*)wcats;
#pragma unroll
    for (int i = t; i < 2304; i += 1024) ldsB4[i] = ws4[i];

    int wave = t >> 6, lane = t & 63, mrow = lane & 15, quad = lane >> 4;
    int px_l = wave * 16 + mrow;
    int remp = rem0 + px_l;
    int yp = remp >> 7, xp = remp & 127;
    const ushort_t* xb = xnb + (size_t)b * HW * CIN + quad * 8;

    // preload all 9 taps (loads all independent)
    uint4 af0[9], af1[9];
#pragma unroll
    for (int kk = 0; kk < 9; ++kk) {
        int yy = yp + kk / 3 - 1;
        int xq = xp + kk % 3 - 1;
        bool ok = (yy >= 0) && (yy < H_) && (xq >= 0) && (xq < W_);
        const ushort_t* src = xb + (size_t)(yy * W_ + xq) * CIN;
        af0[kk] = ok ? *(const uint4*)src        : make_uint4(0, 0, 0, 0);
        af1[kk] = ok ? *(const uint4*)(src + 32) : make_uint4(0, 0, 0, 0);
    }
    __syncthreads();

    f32x4 acc[2];
    acc[0] = (f32x4){0.f, 0.f, 0.f, 0.f};
    acc[1] = (f32x4){0.f, 0.f, 0.f, 0.f};
    const ushort_t* ldsB = (const ushort_t*)ldsB4;
#pragma unroll
    for (int kk = 0; kk < 9; ++kk) {
#pragma unroll
        for (int half = 0; half < 2; ++half) {
            int ks = kk * 2 + half;
            U4B a; a.u = half ? af1[kk] : af0[kk];
#pragma unroll
            for (int n = 0; n < 2; ++n) {
                bf16x8 bf = *(const bf16x8*)(ldsB + ((ks * 2 + n) * 64 + lane) * 8);
                acc[n] = __builtin_amdgcn_mfma_f32_16x16x32_bf16(a.v, bf, acc[n], 0, 0, 0);
            }
        }
    }

    // epilogue
#pragma unroll
    for (int n = 0; n < 2; ++n) {
        int co2 = n * 16 + mrow;
        if (co2 >= 27) continue;
        float bs = bias[co2];
#pragma unroll
        for (int r = 0; r < 4; ++r) {
            int px = wave * 16 + quad * 4 + r;
            float v = acc[n][r] + bs;
            if (co2 < 18) {
                off2[((size_t)(b * 9 + (co2 >> 1)) * HW + rem0 + px) * 2 + (co2 & 1)] = v;
            } else {
                mask_ws[(size_t)(b * 9 + (co2 - 18)) * HW + rem0 + px] =
                    1.0f / (1.0f + __expf(-v));
            }
        }
    }
}

// ---------------------------------------------------------------------------
// deform_mfma helpers.
// issue_tap: addresses+loads for one tap, clamped, no divergence. Mask mk is
// folded into the 4 bilinear corner weights here (numerically equivalent,
// removes 16 v_mul from consume). 32-bit offsets hoisted across corners.
// ---------------------------------------------------------------------------
__device__ __forceinline__ void issue_tap(int yp_t, int xp_t,
                                          float oy, float ox, float mk,
                                          const ushort_t* __restrict__ xb,
                                          uint4* cb, float* wg) {
    float py  = (float)yp_t + oy;
    float pxf = (float)xp_t + ox;
    float y0f = floorf(py), x0f = floorf(pxf);
    int yi = (int)y0f, xi = (int)x0f;
    float wy1 = py - y0f, wx1 = pxf - x0f;
    float wy0 = 1.0f - wy1, wx0 = 1.0f - wx1;
    int ya  = min(max(yi, 0), H_ - 1);
    int yb  = min(max(yi + 1, 0), H_ - 1);
    int xa  = min(max(xi, 0), W_ - 1);
    int xb2 = min(max(xi + 1, 0), W_ - 1);
    bool vy0 = (yi >= 0) & (yi < H_);
    bool vy1 = (yi >= -1) & (yi < H_ - 1);
    bool vx0 = (xi >= 0) & (xi < W_);
    bool vx1 = (xi >= -1) & (xi < W_ - 1);
    float m0 = mk * wy0, m1 = mk * wy1;
    wg[0] = (vy0 & vx0) ? m0 * wx0 : 0.0f;
    wg[1] = (vy0 & vx1) ? m0 * wx1 : 0.0f;
    wg[2] = (vy1 & vx0) ? m1 * wx0 : 0.0f;
    wg[3] = (vy1 & vx1) ? m1 * wx1 : 0.0f;
    int ra = ya << 13, rb = yb << 13;   // y * W_ * CIN
    int ca = xa << 6,  cb_ = xb2 << 6;  // x * CIN
    const ushort_t* s00 = xb + (ra + ca);
    const ushort_t* s01 = xb + (ra + cb_);
    const ushort_t* s10 = xb + (rb + ca);
    const ushort_t* s11 = xb + (rb + cb_);
    cb[0] = *(const uint4*)s00;
    cb[1] = *(const uint4*)(s00 + 32);
    cb[2] = *(const uint4*)s01;
    cb[3] = *(const uint4*)(s01 + 32);
    cb[4] = *(const uint4*)s10;
    cb[5] = *(const uint4*)(s10 + 32);
    cb[6] = *(const uint4*)s11;
    cb[7] = *(const uint4*)(s11 + 32);
}

__device__ __forceinline__ void consume_tap(int kk, const uint4* cb,
                                            const float* wg,
                                            const ushort_t* __restrict__ ldsB,
                                            int lane, f32x4* acc) {
    float2 v2[8];
#pragma unroll
    for (int j = 0; j < 8; ++j) v2[j] = make_float2(0.f, 0.f);
#pragma unroll
    for (int c = 0; c < 4; ++c) {
        float w = wg[c];
        unsigned int ww[8] = {cb[2 * c].x,     cb[2 * c].y,
                              cb[2 * c].z,     cb[2 * c].w,
                              cb[2 * c + 1].x, cb[2 * c + 1].y,
                              cb[2 * c + 1].z, cb[2 * c + 1].w};
#pragma unroll
        for (int j = 0; j < 8; ++j) {
            v2[j].x = fmaf(w, lo_f(ww[j]), v2[j].x);
            v2[j].y = fmaf(w, hi_f(ww[j]), v2[j].y);
        }
    }
    unsigned int w8[8];
#pragma unroll
    for (int j = 0; j < 8; ++j)
        w8[j] = pack2(v2[j].x, v2[j].y);
    U4B a0, a1;
    a0.u = make_uint4(w8[0], w8[1], w8[2], w8[3]);
    a1.u = make_uint4(w8[4], w8[5], w8[6], w8[7]);
#pragma unroll
    for (int half = 0; half < 2; ++half) {
        int ks = kk * 2 + half;
        U4B a = half ? a1 : a0;
        const ushort_t* bbase = ldsB + ((size_t)(ks * 8) * 64 + lane) * 8;
#pragma unroll
        for (int n = 0; n < 8; ++n) {
            bf16x8 bf = *(const bf16x8*)(bbase + n * 64 * 8);
            acc[n] = __builtin_amdgcn_mfma_f32_16x16x32_bf16(a.v, bf, acc[n], 0, 0, 0);
        }
    }
}

// ---------------------------------------------------------------------------
// deform_mfma: fused bilinear sampling + GEMM. 1024 thr / 256 px / 16 waves.
// B = full W^T (147 KB fragment-linear) staged once; ONE barrier; then each
// wave runs a software-pipelined tap loop. The pipeline is ENFORCED with
// __builtin_amdgcn_sched_barrier(0) after each issue phase — without it the
// compiler sinks the gather loads to their uses (evidence: VGPR_Count=64,
// impossible with cb0+cb1+acc >= 96 live) and every tap eats full gather
// latency. Offsets/mask are pipelined 2-deep (2-slot parity) instead of all
// 27 upfront to stay under the 128-VGPR cap at 4 waves/SIMD.
// ---------------------------------------------------------------------------
__global__ __launch_bounds__(1024, 4) void deform_mfma(
        const ushort_t* __restrict__ xnb,
        const float* __restrict__ off2,
        const float* __restrict__ mask_ws,
        const ushort_t* __restrict__ wTs,
        ushort_t* __restrict__ prebn,
        float* __restrict__ gstat) {
    __shared__ uint4 ldsB4[9216];    // 147,456 B
    __shared__ float red[256];

    int t    = threadIdx.x;
    int pix0 = blockIdx.x * 256;
    int b    = pix0 >> 14;
    int rem0 = pix0 & 16383;

    const uint4* ws4 = (const uint4*)wTs;
#pragma unroll
    for (int i = 0; i < 9; ++i) ldsB4[i * 1024 + t] = ws4[i * 1024 + t];
    if (t < 256) red[t] = 0.0f;

    int wave = t >> 6, lane = t & 63, mrow = lane & 15, quad = lane >> 4;
    int px_l = wave * 16 + mrow;
    int remp = rem0 + px_l;
    int yp = remp >> 7, xp = remp & 127;
    const ushort_t* xb = xnb + (size_t)b * HW * CIN + quad * 8;
    size_t obase = (size_t)b * 9 * HW + remp;

    // 2-slot pipelined offset/mask prefetch: taps 0 and 1 before the barrier.
    float2 o0 = *(const float2*)(off2 + obase * 2);
    float2 o1 = *(const float2*)(off2 + (obase + HW) * 2);
    float mk0 = mask_ws[obase];
    float mk1 = mask_ws[obase + HW];
    __syncthreads();

    f32x4 acc[8];
#pragma unroll
    for (int n = 0; n < 8; ++n) acc[n] = (f32x4){0.f, 0.f, 0.f, 0.f};
    const ushort_t* ldsB = (const ushort_t*)ldsB4;

    // software-pipelined tap loop (gathers lookahead 1, offsets lookahead 2)
    uint4 cb0[8], cb1[8];
    float wg0[4], wg1[4];
    issue_tap(yp - 1, xp - 1, o0.x, o0.y, mk0, xb, cb0, wg0);
    __builtin_amdgcn_sched_barrier(0);
#pragma unroll
    for (int kk = 0; kk < 9; ++kk) {
        if ((kk & 1) == 0) {
            if (kk < 7) {
                o0  = *(const float2*)(off2 + (obase + (size_t)(kk + 2) * HW) * 2);
                mk0 = mask_ws[obase + (size_t)(kk + 2) * HW];
            }
            if (kk < 8)
                issue_tap(yp + (kk + 1) / 3 - 1, xp + (kk + 1) % 3 - 1,
                          o1.x, o1.y, mk1, xb, cb1, wg1);
            __builtin_amdgcn_sched_barrier(0);
            consume_tap(kk, cb0, wg0, ldsB, lane, acc);
        } else {
            if (kk < 7) {
                o1  = *(const float2*)(off2 + (obase + (size_t)(kk + 2) * HW) * 2);
                mk1 = mask_ws[obase + (size_t)(kk + 2) * HW];
            }
            if (kk < 8)
                issue_tap(yp + (kk + 1) / 3 - 1, xp + (kk + 1) % 3 - 1,
                          o0.x, o0.y, mk0, xb, cb0, wg0);
            __builtin_amdgcn_sched_barrier(0);
            consume_tap(kk, cb1, wg1, ldsB, lane, acc);
        }
    }

    // ---- epilogue: bf16 NHWC store + BN stats (shuffle-reduce) ----
#pragma unroll
    for (int n = 0; n < 8; ++n) {
        int co = n * 16 + mrow;
        float s = 0.f, ss = 0.f;
#pragma unroll
        for (int r = 0; r < 4; ++r) {
            int pg = pix0 + wave * 16 + quad * 4 + r;
            float v = acc[n][r];
            prebn[(size_t)pg * COUT + co] = f2us_bf(v);
            s += v;
            ss += v * v;
        }
        s  += __shfl_xor(s, 16, 64);
        s  += __shfl_xor(s, 32, 64);
        ss += __shfl_xor(ss, 16, 64);
        ss += __shfl_xor(ss, 32, 64);
        if (quad == 0) {
            atomicAdd(&red[co], s);
            atomicAdd(&red[128 + co], ss);
        }
    }
    __syncthreads();
    if (t < 256) atomicAdd(&gstat[(blockIdx.x & 15) * 256 + t], red[t]);
}

// ---------------------------------------------------------------------------
// bn_apply_t: derive mean/rstd from gstat per block (cheap), then read pre-BN
// bf16 NHWC, normalize+ReLU, write f32 NCHW d_out via LDS transpose tile.
// ---------------------------------------------------------------------------
__global__ __launch_bounds__(256) void bn_apply_t(const ushort_t* __restrict__ prebn,
                                                  const float* __restrict__ gstat,
                                                  float* __restrict__ out) {
    __shared__ float tile[128 * 65];
    __shared__ float mvs[256];
    int t = threadIdx.x;
    if (t < 128) {
        float s = 0.f, ss = 0.f;
#pragma unroll
        for (int part = 0; part < 16; ++part) {
            s  += gstat[part * 256 + t];
            ss += gstat[part * 256 + 128 + t];
        }
        const float invN = 1.0f / (float)NPIX;
        float mean = s * invN;
        float var  = ss * invN - mean * mean;
        if (!isfinite(mean)) mean = 0.0f;
        float r = rsqrtf(fmaxf(var, 0.0f) + 1e-5f);
        if (!isfinite(r)) r = 1.0f;
        mvs[t]       = mean;
        mvs[128 + t] = r;
    }
    __syncthreads();
    int pix0 = blockIdx.x * 64;
    int b    = pix0 >> 14;
    int rem0 = pix0 & 16383;
    const ushort_t* src = prebn + (size_t)pix0 * COUT;
#pragma unroll
    for (int r = 0; r < 32; ++r) {
        int i = r * 256 + t;
        int p = i >> 7, c = i & 127;
        float v = us2f(src[i]);
        v = fmaxf((v - mvs[c]) * mvs[128 + c], 0.0f);
        tile[c * 65 + p] = v;
    }
    __syncthreads();
#pragma unroll
    for (int r = 0; r < 32; ++r) {
        int i = r * 256 + t;
        int c2 = i >> 6, p2 = i & 63;
        out[(size_t)(b * COUT + c2) * HW + rem0 + p2] = tile[c2 * 65 + p2];
    }
}

// ---------------------------------------------------------------------------
extern "C" void kernel_launch(void* const* d_in, const int* in_sizes, int n_in,
                              void* d_out, int out_size, void* d_ws, size_t ws_size,
                              hipStream_t stream) {
    (void)in_sizes; (void)n_in; (void)out_size; (void)ws_size;
    const void* x     = d_in[0];
    const void* offw  = d_in[1];
    const void* offb  = d_in[2];
    const void* maskw = d_in[3];
    const void* maskb = d_in[4];
    const void* convw = d_in[5];

    float* ws       = (float*)d_ws;
    float* off2     = ws;                      // 2,359,296 f32 (y,x interleaved)
    float* mask_ws  = off2 + 2359296;          // 1,179,648 f32
    float* bias     = mask_ws + 1179648;       //        32 f32
    float* gstat    = bias + 32;               //     4,096 f32
    float* flag     = gstat + 4096;            //        16 f32
    ushort_t* wTs   = (ushort_t*)(flag + 16);  //    73,728 bf16 (frag-linear)
    ushort_t* wcats = wTs + 73728;             //    18,432 bf16 (frag-linear)
    ushort_t* xnb   = wcats + 18432;           // 8,388,608 bf16 (NHWC x)
    ushort_t* prebn = xnb + 8388608;           // 16,777,216 bf16 (NHWC pre-BN)
    float* out      = (float*)d_out;

    detect_zero<<<1, 256, 0, stream>>>((const uint4*)x, flag, gstat);
    prep_weights<<<361, 256, 0, stream>>>(offw, offb, maskw, maskb, convw, flag, wTs, wcats, bias);
    transpose_x<<<2048, 256, 0, stream>>>(x, flag, xnb);
    conv_mfma<<<512, 1024, 0, stream>>>(xnb, wcats, bias, off2, mask_ws);
    deform_mfma<<<512, 1024, 0, stream>>>(xnb, off2, mask_ws, wTs, prebn, gstat);
    bn_apply_t<<<2048, 256, 0, stream>>>(prebn, gstat, out);
}

// Round 2
// 219.828 us; speedup vs baseline: 1.0581x; 1.0581x over previous
//
#include <hip/hip_runtime.h>
#include <hip/hip_bf16.h>

// Problem constants
#define H_ 128
#define W_ 128
#define HW 16384          // H*W
#define CIN 64
#define COUT 128
#define KK9 9
#define BATCH 8
#define NPIX (BATCH * HW) // 131072
#define KDIM 576          // CIN*KK9

typedef short bf16x8 __attribute__((ext_vector_type(8)));
typedef float f32x4  __attribute__((ext_vector_type(4)));
typedef unsigned short ushort_t;

union U4B { uint4 u; bf16x8 v; };

__device__ __forceinline__ float us2f(unsigned short u) {
    unsigned int v = ((unsigned int)u) << 16;
    float f;
    __builtin_memcpy(&f, &v, 4);
    return f;
}
__device__ __forceinline__ float lo_f(unsigned int w) {
    unsigned int v = w << 16;
    float f;
    __builtin_memcpy(&f, &v, 4);
    return f;
}
__device__ __forceinline__ float hi_f(unsigned int w) {
    unsigned int v = w & 0xffff0000u;
    float f;
    __builtin_memcpy(&f, &v, 4);
    return f;
}
__device__ __forceinline__ unsigned short f2us_bf(float f) {
    __hip_bfloat16 h = __float2bfloat16(f);
    unsigned short u;
    __builtin_memcpy(&u, &h, 2);
    return u;
}
__device__ __forceinline__ unsigned int pack2(float a, float b) {
    return (unsigned int)f2us_bf(a) | ((unsigned int)f2us_bf(b) << 16);
}

template <bool F32>
__device__ __forceinline__ float ld_in(const void* p, long i) {
    if (F32) return ((const float*)p)[i];
    return us2f(((const unsigned short*)p)[i]);
}

// ---------------------------------------------------------------------------
// detect_zero: dtype probe (1 wave, vector loads, ballot) + zero gstat.
// ---------------------------------------------------------------------------
__global__ void detect_zero(const uint4* __restrict__ xr4,
                            float* __restrict__ flag,
                            float* __restrict__ gstat) {
    int t = threadIdx.x;   // 256
#pragma unroll
    for (int i = 0; i < 16; ++i) gstat[i * 256 + t] = 0.0f;
    if (t < 64) {
        uint4 v = xr4[t];
        unsigned int w[4] = {v.x, v.y, v.z, v.w};
        int big = 0;
#pragma unroll
        for (int q = 0; q < 4; ++q) {
            big += (((w[q] >> 7)  & 0xFF) >= 0xC0);
            big += (((w[q] >> 23) & 0xFF) >= 0xC0);
        }
        unsigned long long m = __ballot(big > 0);
        if (t == 0) flag[0] = m ? 1.0f : 0.0f;
    }
}

// ---------------------------------------------------------------------------
// prep_weights: weights in MFMA-fragment-linear order. Single kernel,
// internal wave-uniform branch on flag.
// ---------------------------------------------------------------------------
template <bool F32>
__device__ __forceinline__ void prep_body(const void* offw, const void* offb,
                                          const void* maskw, const void* maskb,
                                          const void* convw,
                                          ushort_t* wTs, ushort_t* wcats,
                                          float* bias, int i) {
    if (i < 73728) {
        int j = i & 7, lane = (i >> 3) & 63, n = (i >> 9) & 7, ks = i >> 12;
        int co = n * 16 + (lane & 15);
        int k  = ks * 32 + ((lane >> 4) << 3) + j;
        int kk = k >> 6, ci = k & 63;
        wTs[i] = f2us_bf(ld_in<F32>(convw, (long)co * KDIM + ci * 9 + kk));
    } else if (i < 73728 + 18432) {
        int i2 = i - 73728;
        int j = i2 & 7, lane = (i2 >> 3) & 63, n = (i2 >> 9) & 1, ks = i2 >> 10;
        int co2 = n * 16 + (lane & 15);
        int k   = ks * 32 + ((lane >> 4) << 3) + j;
        int kk = k >> 6, ci = k & 63;
        float v = 0.0f;
        if (co2 < 18)      v = ld_in<F32>(offw,  (long)co2 * KDIM + ci * 9 + kk);
        else if (co2 < 27) v = ld_in<F32>(maskw, (long)(co2 - 18) * KDIM + ci * 9 + kk);
        wcats[i2] = f2us_bf(v);
    } else if (i < 73728 + 18432 + 32) {
        int j = i - 73728 - 18432;
        float v = 0.0f;
        if (j < 18)      v = ld_in<F32>(offb, j);
        else if (j < 27) v = ld_in<F32>(maskb, j - 18);
        bias[j] = v;
    }
}

__global__ void prep_weights(const void* __restrict__ offw,
                             const void* __restrict__ offb,
                             const void* __restrict__ maskw,
                             const void* __restrict__ maskb,
                             const void* __restrict__ convw,
                             const float* __restrict__ flag,
                             ushort_t* __restrict__ wTs,
                             ushort_t* __restrict__ wcats,
                             float* __restrict__ bias) {
    int i = blockIdx.x * 256 + threadIdx.x;
    if (flag[0] != 0.0f)
        prep_body<true>(offw, offb, maskw, maskb, convw, wTs, wcats, bias, i);
    else
        prep_body<false>(offw, offb, maskw, maskb, convw, wTs, wcats, bias, i);
}

// ---------------------------------------------------------------------------
// transpose_x: raw x NCHW -> NHWC bf16. Single kernel, internal flag branch.
// ---------------------------------------------------------------------------
template <bool F32>
__device__ __forceinline__ void transpose_body(const void* x, ushort_t* xnb) {
    __shared__ float tile[CIN][64 + 1];
    int blk  = blockIdx.x;
    int b    = blk >> 8;
    int pix0 = (blk & 255) * 64;
    int t    = threadIdx.x;
    int lane = t & 63;
    int grp  = t >> 6;
#pragma unroll
    for (int r = 0; r < 16; ++r) {
        int ci = r * 4 + grp;
        tile[ci][lane] = ld_in<F32>(x, (long)(b * CIN + ci) * HW + pix0 + lane);
    }
    __syncthreads();
#pragma unroll
    for (int r = 0; r < 16; ++r) {
        int px = r * 4 + grp;
        xnb[(size_t)(b * HW + pix0 + px) * CIN + lane] = f2us_bf(tile[lane][px]);
    }
}

__global__ __launch_bounds__(256) void transpose_x(const void* __restrict__ x,
                                                   const float* __restrict__ flag,
                                                   ushort_t* __restrict__ xnb) {
    if (flag[0] != 0.0f) transpose_body<true>(x, xnb);
    else                 transpose_body<false>(x, xnb);
}

// ---------------------------------------------------------------------------
// conv_mfma: implicit-GEMM 3x3 conv -> 27 ch. 1024 thr / 256 px / 16 waves.
// ---------------------------------------------------------------------------
__global__ __launch_bounds__(1024, 4) void conv_mfma(
        const ushort_t* __restrict__ xnb,
        const ushort_t* __restrict__ wcats,
        const float* __restrict__ bias,
        float* __restrict__ off2,
        float* __restrict__ mask_ws) {
    __shared__ uint4 ldsB4[2304];    // 36,864 B

    int t    = threadIdx.x;
    int pix0 = blockIdx.x * 256;
    int b    = pix0 >> 14;
    int rem0 = pix0 & 16383;

    const uint4* ws4 = (const uint4*)wcats;
#pragma unroll
    for (int i = t; i < 2304; i += 1024) ldsB4[i] = ws4[i];

    int wave = t >> 6, lane = t & 63, mrow = lane & 15, quad = lane >> 4;
    int px_l = wave * 16 + mrow;
    int remp = rem0 + px_l;
    int yp = remp >> 7, xp = remp & 127;
    const ushort_t* xb = xnb + (size_t)b * HW * CIN + quad * 8;

    // preload all 9 taps (loads all independent)
    uint4 af0[9], af1[9];
#pragma unroll
    for (int kk = 0; kk < 9; ++kk) {
        int yy = yp + kk / 3 - 1;
        int xq = xp + kk % 3 - 1;
        bool ok = (yy >= 0) && (yy < H_) && (xq >= 0) && (xq < W_);
        const ushort_t* src = xb + (size_t)(yy * W_ + xq) * CIN;
        af0[kk] = ok ? *(const uint4*)src        : make_uint4(0, 0, 0, 0);
        af1[kk] = ok ? *(const uint4*)(src + 32) : make_uint4(0, 0, 0, 0);
    }
    __syncthreads();

    f32x4 acc[2];
    acc[0] = (f32x4){0.f, 0.f, 0.f, 0.f};
    acc[1] = (f32x4){0.f, 0.f, 0.f, 0.f};
    const ushort_t* ldsB = (const ushort_t*)ldsB4;
#pragma unroll
    for (int kk = 0; kk < 9; ++kk) {
#pragma unroll
        for (int half = 0; half < 2; ++half) {
            int ks = kk * 2 + half;
            U4B a; a.u = half ? af1[kk] : af0[kk];
#pragma unroll
            for (int n = 0; n < 2; ++n) {
                bf16x8 bf = *(const bf16x8*)(ldsB + ((ks * 2 + n) * 64 + lane) * 8);
                acc[n] = __builtin_amdgcn_mfma_f32_16x16x32_bf16(a.v, bf, acc[n], 0, 0, 0);
            }
        }
    }

    // epilogue
#pragma unroll
    for (int n = 0; n < 2; ++n) {
        int co2 = n * 16 + mrow;
        if (co2 >= 27) continue;
        float bs = bias[co2];
#pragma unroll
        for (int r = 0; r < 4; ++r) {
            int px = wave * 16 + quad * 4 + r;
            float v = acc[n][r] + bs;
            if (co2 < 18) {
                off2[((size_t)(b * 9 + (co2 >> 1)) * HW + rem0 + px) * 2 + (co2 & 1)] = v;
            } else {
                mask_ws[(size_t)(b * 9 + (co2 - 18)) * HW + rem0 + px] =
                    1.0f / (1.0f + __expf(-v));
            }
        }
    }
}

// ---------------------------------------------------------------------------
// deform_mfma helpers — HALF-TAP pipeline granularity.
// compute_tap: addresses (element offsets) + mask-folded bilinear weights.
// issue_half: 4 corner loads of ONE 8-channel half (4 uint4 = 16 VGPR).
// consume_half: interp 4 words + pack + 8 MFMAs for one k-slot ks.
// Half buffers (16+16 VGPR) instead of full-tap (32+32) keep the pinned
// pipeline under the 128-reg/wave cap (16-wave block + 148KB LDS => 4
// waves/SIMD MUST fit). Round-1 full-tap version spilled to scratch
// (VGPR=64 + FETCH/WRITE +23/+36MB = spill traffic).
// ---------------------------------------------------------------------------
__device__ __forceinline__ void compute_tap(int yp_t, int xp_t,
                                            float oy, float ox, float mk,
                                            int* ofs, float* wg) {
    float py  = (float)yp_t + oy;
    float pxf = (float)xp_t + ox;
    float y0f = floorf(py), x0f = floorf(pxf);
    int yi = (int)y0f, xi = (int)x0f;
    float wy1 = py - y0f, wx1 = pxf - x0f;
    float wy0 = 1.0f - wy1, wx0 = 1.0f - wx1;
    int ya  = min(max(yi, 0), H_ - 1);
    int yb  = min(max(yi + 1, 0), H_ - 1);
    int xa  = min(max(xi, 0), W_ - 1);
    int xb2 = min(max(xi + 1, 0), W_ - 1);
    bool vy0 = (yi >= 0) & (yi < H_);
    bool vy1 = (yi >= -1) & (yi < H_ - 1);
    bool vx0 = (xi >= 0) & (xi < W_);
    bool vx1 = (xi >= -1) & (xi < W_ - 1);
    float m0 = mk * wy0, m1 = mk * wy1;
    wg[0] = (vy0 & vx0) ? m0 * wx0 : 0.0f;
    wg[1] = (vy0 & vx1) ? m0 * wx1 : 0.0f;
    wg[2] = (vy1 & vx0) ? m1 * wx0 : 0.0f;
    wg[3] = (vy1 & vx1) ? m1 * wx1 : 0.0f;
    int ra = ya << 13, rb = yb << 13;   // y * W_ * CIN
    int ca = xa << 6,  cb_ = xb2 << 6;  // x * CIN
    ofs[0] = ra + ca;  ofs[1] = ra + cb_;
    ofs[2] = rb + ca;  ofs[3] = rb + cb_;
}

__device__ __forceinline__ void issue_half(const ushort_t* __restrict__ xb,
                                           const int* ofs, int hoff, uint4* cb) {
#pragma unroll
    for (int c = 0; c < 4; ++c)
        cb[c] = *(const uint4*)(xb + ofs[c] + hoff);
}

__device__ __forceinline__ void consume_half(int ks, const uint4* cb,
                                             const float* wg,
                                             const ushort_t* __restrict__ ldsB,
                                             int lane, f32x4* acc) {
    float2 v2[4];
#pragma unroll
    for (int j = 0; j < 4; ++j) v2[j] = make_float2(0.f, 0.f);
#pragma unroll
    for (int c = 0; c < 4; ++c) {
        float w = wg[c];
        unsigned int ww[4] = {cb[c].x, cb[c].y, cb[c].z, cb[c].w};
#pragma unroll
        for (int j = 0; j < 4; ++j) {
            v2[j].x = fmaf(w, lo_f(ww[j]), v2[j].x);
            v2[j].y = fmaf(w, hi_f(ww[j]), v2[j].y);
        }
    }
    U4B a;
    a.u = make_uint4(pack2(v2[0].x, v2[0].y), pack2(v2[1].x, v2[1].y),
                     pack2(v2[2].x, v2[2].y), pack2(v2[3].x, v2[3].y));
    const ushort_t* bbase = ldsB + ((size_t)(ks * 8) * 64 + lane) * 8;
#pragma unroll
    for (int n = 0; n < 8; ++n) {
        bf16x8 bf = *(const bf16x8*)(bbase + n * 64 * 8);
        acc[n] = __builtin_amdgcn_mfma_f32_16x16x32_bf16(a.v, bf, acc[n], 0, 0, 0);
    }
}

// ---------------------------------------------------------------------------
// deform_mfma: fused bilinear sampling + GEMM. 1024 thr / 256 px / 16 waves.
// B = full W^T (147 KB fragment-linear) staged once; ONE barrier; then a
// half-tap software pipeline: 18 half-steps, each {issue next half's 4
// corner loads -> sched_barrier(0) -> consume current half}. Pipeline is
// schedule-pinned; payload sized to fit 128 regs/wave (no spill).
// Offsets/masks pipelined 2-deep (even/odd tap slots).
// ---------------------------------------------------------------------------
__global__ __launch_bounds__(1024, 4) void deform_mfma(
        const ushort_t* __restrict__ xnb,
        const float* __restrict__ off2,
        const float* __restrict__ mask_ws,
        const ushort_t* __restrict__ wTs,
        ushort_t* __restrict__ prebn,
        float* __restrict__ gstat) {
    __shared__ uint4 ldsB4[9216];    // 147,456 B
    __shared__ float red[256];

    int t    = threadIdx.x;
    int pix0 = blockIdx.x * 256;
    int b    = pix0 >> 14;
    int rem0 = pix0 & 16383;

    const uint4* ws4 = (const uint4*)wTs;
#pragma unroll
    for (int i = 0; i < 9; ++i) ldsB4[i * 1024 + t] = ws4[i * 1024 + t];
    if (t < 256) red[t] = 0.0f;

    int wave = t >> 6, lane = t & 63, mrow = lane & 15, quad = lane >> 4;
    int px_l = wave * 16 + mrow;
    int remp = rem0 + px_l;
    int yp = remp >> 7, xp = remp & 127;
    const ushort_t* xb = xnb + (size_t)b * HW * CIN + quad * 8;
    size_t obase = (size_t)b * 9 * HW + remp;

    // 2-slot (even/odd tap) offset+mask prefetch: taps 0 and 1 pre-barrier.
    float2 oE = *(const float2*)(off2 + obase * 2);
    float2 oO = *(const float2*)(off2 + (obase + HW) * 2);
    float mkE = mask_ws[obase];
    float mkO = mask_ws[obase + HW];
    __syncthreads();

    f32x4 acc[8];
#pragma unroll
    for (int n = 0; n < 8; ++n) acc[n] = (f32x4){0.f, 0.f, 0.f, 0.f};
    const ushort_t* ldsB = (const ushort_t*)ldsB4;

    // addr/weight slots indexed by tap parity; data buffers by half-step parity
    int   ofs[2][4];
    float wg[2][4];
    uint4 cb[2][4];

    compute_tap(yp - 1, xp - 1, oE.x, oE.y, mkE, ofs[0], wg[0]);
    issue_half(xb, ofs[0], 0, cb[0]);
    __builtin_amdgcn_sched_barrier(0);

#pragma unroll
    for (int hs = 0; hs < 18; ++hs) {
        const int kk = hs >> 1;   // current tap
        const int h  = hs & 1;    // current half
        const int tp = kk & 1;    // addr slot of current tap
        const int bp = hs & 1;    // data buffer of current half-step
        if (h == 0) {
            // issue (kk, half1) into the other buffer (same tap addresses)
            issue_half(xb, ofs[tp], 32, cb[bp ^ 1]);
        } else {
            if (kk < 8) {
                const int nt = kk + 1;
                float ooy = (nt & 1) ? oO.x : oE.x;
                float oox = (nt & 1) ? oO.y : oE.y;
                float omk = (nt & 1) ? mkO : mkE;
                compute_tap(yp + nt / 3 - 1, xp + nt % 3 - 1, ooy, oox, omk,
                            ofs[tp ^ 1], wg[tp ^ 1]);
                issue_half(xb, ofs[tp ^ 1], 0, cb[bp ^ 1]);
            }
            if (kk < 7) {
                const int pt = kk + 2;   // parity == tp
                float2 o = *(const float2*)(off2 + (obase + (size_t)pt * HW) * 2);
                float  m = mask_ws[obase + (size_t)pt * HW];
                if (tp) { oO = o; mkO = m; } else { oE = o; mkE = m; }
            }
        }
        __builtin_amdgcn_sched_barrier(0);
        consume_half(hs, cb[bp], wg[tp], ldsB, lane, acc);
    }

    // ---- epilogue: bf16 NHWC store + BN stats (shuffle-reduce) ----
#pragma unroll
    for (int n = 0; n < 8; ++n) {
        int co = n * 16 + mrow;
        float s = 0.f, ss = 0.f;
#pragma unroll
        for (int r = 0; r < 4; ++r) {
            int pg = pix0 + wave * 16 + quad * 4 + r;
            float v = acc[n][r];
            prebn[(size_t)pg * COUT + co] = f2us_bf(v);
            s += v;
            ss += v * v;
        }
        s  += __shfl_xor(s, 16, 64);
        s  += __shfl_xor(s, 32, 64);
        ss += __shfl_xor(ss, 16, 64);
        ss += __shfl_xor(ss, 32, 64);
        if (quad == 0) {
            atomicAdd(&red[co], s);
            atomicAdd(&red[128 + co], ss);
        }
    }
    __syncthreads();
    if (t < 256) atomicAdd(&gstat[(blockIdx.x & 15) * 256 + t], red[t]);
}

// ---------------------------------------------------------------------------
// bn_apply_t: derive mean/rstd from gstat per block (cheap), then read pre-BN
// bf16 NHWC, normalize+ReLU, write f32 NCHW d_out via LDS transpose tile.
// ---------------------------------------------------------------------------
__global__ __launch_bounds__(256) void bn_apply_t(const ushort_t* __restrict__ prebn,
                                                  const float* __restrict__ gstat,
                                                  float* __restrict__ out) {
    __shared__ float tile[128 * 65];
    __shared__ float mvs[256];
    int t = threadIdx.x;
    if (t < 128) {
        float s = 0.f, ss = 0.f;
#pragma unroll
        for (int part = 0; part < 16; ++part) {
            s  += gstat[part * 256 + t];
            ss += gstat[part * 256 + 128 + t];
        }
        const float invN = 1.0f / (float)NPIX;
        float mean = s * invN;
        float var  = ss * invN - mean * mean;
        if (!isfinite(mean)) mean = 0.0f;
        float r = rsqrtf(fmaxf(var, 0.0f) + 1e-5f);
        if (!isfinite(r)) r = 1.0f;
        mvs[t]       = mean;
        mvs[128 + t] = r;
    }
    __syncthreads();
    int pix0 = blockIdx.x * 64;
    int b    = pix0 >> 14;
    int rem0 = pix0 & 16383;
    const ushort_t* src = prebn + (size_t)pix0 * COUT;
#pragma unroll
    for (int r = 0; r < 32; ++r) {
        int i = r * 256 + t;
        int p = i >> 7, c = i & 127;
        float v = us2f(src[i]);
        v = fmaxf((v - mvs[c]) * mvs[128 + c], 0.0f);
        tile[c * 65 + p] = v;
    }
    __syncthreads();
#pragma unroll
    for (int r = 0; r < 32; ++r) {
        int i = r * 256 + t;
        int c2 = i >> 6, p2 = i & 63;
        out[(size_t)(b * COUT + c2) * HW + rem0 + p2] = tile[c2 * 65 + p2];
    }
}

// ---------------------------------------------------------------------------
extern "C" void kernel_launch(void* const* d_in, const int* in_sizes, int n_in,
                              void* d_out, int out_size, void* d_ws, size_t ws_size,
                              hipStream_t stream) {
    (void)in_sizes; (void)n_in; (void)out_size; (void)ws_size;
    const void* x     = d_in[0];
    const void* offw  = d_in[1];
    const void* offb  = d_in[2];
    const void* maskw = d_in[3];
    const void* maskb = d_in[4];
    const void* convw = d_in[5];

    float* ws       = (float*)d_ws;
    float* off2     = ws;                      // 2,359,296 f32 (y,x interleaved)
    float* mask_ws  = off2 + 2359296;          // 1,179,648 f32
    float* bias     = mask_ws + 1179648;       //        32 f32
    float* gstat    = bias + 32;               //     4,096 f32
    float* flag     = gstat + 4096;            //        16 f32
    ushort_t* wTs   = (ushort_t*)(flag + 16);  //    73,728 bf16 (frag-linear)
    ushort_t* wcats = wTs + 73728;             //    18,432 bf16 (frag-linear)
    ushort_t* xnb   = wcats + 18432;           // 8,388,608 bf16 (NHWC x)
    ushort_t* prebn = xnb + 8388608;           // 16,777,216 bf16 (NHWC pre-BN)
    float* out      = (float*)d_out;

    detect_zero<<<1, 256, 0, stream>>>((const uint4*)x, flag, gstat);
    prep_weights<<<361, 256, 0, stream>>>(offw, offb, maskw, maskb, convw, flag, wTs, wcats, bias);
    transpose_x<<<2048, 256, 0, stream>>>(x, flag, xnb);
    conv_mfma<<<512, 1024, 0, stream>>>(xnb, wcats, bias, off2, mask_ws);
    deform_mfma<<<512, 1024, 0, stream>>>(xnb, off2, mask_ws, wTs, prebn, gstat);
    bn_apply_t<<<2048, 256, 0, stream>>>(prebn, gstat, out);
}

// Round 3
// 217.871 us; speedup vs baseline: 1.0676x; 1.0090x over previous
//
#include <hip/hip_runtime.h>
#include <hip/hip_bf16.h>

// Problem constants
#define H_ 128
#define W_ 128
#define HW 16384          // H*W
#define CIN 64
#define COUT 128
#define KK9 9
#define BATCH 8
#define NPIX (BATCH * HW) // 131072
#define KDIM 576          // CIN*KK9

typedef short bf16x8 __attribute__((ext_vector_type(8)));
typedef float f32x4  __attribute__((ext_vector_type(4)));
typedef unsigned short ushort_t;

union U4B { uint4 u; bf16x8 v; };

__device__ __forceinline__ float us2f(unsigned short u) {
    unsigned int v = ((unsigned int)u) << 16;
    float f;
    __builtin_memcpy(&f, &v, 4);
    return f;
}
__device__ __forceinline__ float lo_f(unsigned int w) {
    unsigned int v = w << 16;
    float f;
    __builtin_memcpy(&f, &v, 4);
    return f;
}
__device__ __forceinline__ float hi_f(unsigned int w) {
    unsigned int v = w & 0xffff0000u;
    float f;
    __builtin_memcpy(&f, &v, 4);
    return f;
}
__device__ __forceinline__ unsigned short f2us_bf(float f) {
    __hip_bfloat16 h = __float2bfloat16(f);
    unsigned short u;
    __builtin_memcpy(&u, &h, 2);
    return u;
}
__device__ __forceinline__ unsigned int pack2(float a, float b) {
    return (unsigned int)f2us_bf(a) | ((unsigned int)f2us_bf(b) << 16);
}

template <bool F32>
__device__ __forceinline__ float ld_in(const void* p, long i) {
    if (F32) return ((const float*)p)[i];
    return us2f(((const unsigned short*)p)[i]);
}

// ---------------------------------------------------------------------------
// detect_zero: dtype probe (1 wave, vector loads, ballot) + zero gstat.
// ---------------------------------------------------------------------------
__global__ void detect_zero(const uint4* __restrict__ xr4,
                            float* __restrict__ flag,
                            float* __restrict__ gstat) {
    int t = threadIdx.x;   // 256
#pragma unroll
    for (int i = 0; i < 16; ++i) gstat[i * 256 + t] = 0.0f;
    if (t < 64) {
        uint4 v = xr4[t];
        unsigned int w[4] = {v.x, v.y, v.z, v.w};
        int big = 0;
#pragma unroll
        for (int q = 0; q < 4; ++q) {
            big += (((w[q] >> 7)  & 0xFF) >= 0xC0);
            big += (((w[q] >> 23) & 0xFF) >= 0xC0);
        }
        unsigned long long m = __ballot(big > 0);
        if (t == 0) flag[0] = m ? 1.0f : 0.0f;
    }
}

// ---------------------------------------------------------------------------
// prep_weights: weights in MFMA-fragment-linear order. Single kernel,
// internal wave-uniform branch on flag.
// ---------------------------------------------------------------------------
template <bool F32>
__device__ __forceinline__ void prep_body(const void* offw, const void* offb,
                                          const void* maskw, const void* maskb,
                                          const void* convw,
                                          ushort_t* wTs, ushort_t* wcats,
                                          float* bias, int i) {
    if (i < 73728) {
        int j = i & 7, lane = (i >> 3) & 63, n = (i >> 9) & 7, ks = i >> 12;
        int co = n * 16 + (lane & 15);
        int k  = ks * 32 + ((lane >> 4) << 3) + j;
        int kk = k >> 6, ci = k & 63;
        wTs[i] = f2us_bf(ld_in<F32>(convw, (long)co * KDIM + ci * 9 + kk));
    } else if (i < 73728 + 18432) {
        int i2 = i - 73728;
        int j = i2 & 7, lane = (i2 >> 3) & 63, n = (i2 >> 9) & 1, ks = i2 >> 10;
        int co2 = n * 16 + (lane & 15);
        int k   = ks * 32 + ((lane >> 4) << 3) + j;
        int kk = k >> 6, ci = k & 63;
        float v = 0.0f;
        if (co2 < 18)      v = ld_in<F32>(offw,  (long)co2 * KDIM + ci * 9 + kk);
        else if (co2 < 27) v = ld_in<F32>(maskw, (long)(co2 - 18) * KDIM + ci * 9 + kk);
        wcats[i2] = f2us_bf(v);
    } else if (i < 73728 + 18432 + 32) {
        int j = i - 73728 - 18432;
        float v = 0.0f;
        if (j < 18)      v = ld_in<F32>(offb, j);
        else if (j < 27) v = ld_in<F32>(maskb, j - 18);
        bias[j] = v;
    }
}

__global__ void prep_weights(const void* __restrict__ offw,
                             const void* __restrict__ offb,
                             const void* __restrict__ maskw,
                             const void* __restrict__ maskb,
                             const void* __restrict__ convw,
                             const float* __restrict__ flag,
                             ushort_t* __restrict__ wTs,
                             ushort_t* __restrict__ wcats,
                             float* __restrict__ bias) {
    int i = blockIdx.x * 256 + threadIdx.x;
    if (flag[0] != 0.0f)
        prep_body<true>(offw, offb, maskw, maskb, convw, wTs, wcats, bias, i);
    else
        prep_body<false>(offw, offb, maskw, maskb, convw, wTs, wcats, bias, i);
}

// ---------------------------------------------------------------------------
// transpose_x: raw x NCHW -> NHWC bf16. Single kernel, internal flag branch.
// ---------------------------------------------------------------------------
template <bool F32>
__device__ __forceinline__ void transpose_body(const void* x, ushort_t* xnb) {
    __shared__ float tile[CIN][64 + 1];
    int blk  = blockIdx.x;
    int b    = blk >> 8;
    int pix0 = (blk & 255) * 64;
    int t    = threadIdx.x;
    int lane = t & 63;
    int grp  = t >> 6;
#pragma unroll
    for (int r = 0; r < 16; ++r) {
        int ci = r * 4 + grp;
        tile[ci][lane] = ld_in<F32>(x, (long)(b * CIN + ci) * HW + pix0 + lane);
    }
    __syncthreads();
#pragma unroll
    for (int r = 0; r < 16; ++r) {
        int px = r * 4 + grp;
        xnb[(size_t)(b * HW + pix0 + px) * CIN + lane] = f2us_bf(tile[lane][px]);
    }
}

__global__ __launch_bounds__(256) void transpose_x(const void* __restrict__ x,
                                                   const float* __restrict__ flag,
                                                   ushort_t* __restrict__ xnb) {
    if (flag[0] != 0.0f) transpose_body<true>(x, xnb);
    else                 transpose_body<false>(x, xnb);
}

// ---------------------------------------------------------------------------
// conv_mfma: implicit-GEMM 3x3 conv -> 27 ch. 1024 thr / 256 px / 16 waves.
// XCD-chunked block swizzle: XCD k processes exactly batch k (2MB xnb slab
// -> L2-resident gathers).
// ---------------------------------------------------------------------------
__global__ __launch_bounds__(1024, 4) void conv_mfma(
        const ushort_t* __restrict__ xnb,
        const ushort_t* __restrict__ wcats,
        const float* __restrict__ bias,
        float* __restrict__ off2,
        float* __restrict__ mask_ws) {
    __shared__ uint4 ldsB4[2304];    // 36,864 B

    int t    = threadIdx.x;
    int bid  = blockIdx.x;
    int sbid = (bid & 7) * 64 + (bid >> 3);   // 512 = 8 XCDs x 64, bijective
    int pix0 = sbid * 256;
    int b    = pix0 >> 14;
    int rem0 = pix0 & 16383;

    const uint4* ws4 = (const uint4*)wcats;
#pragma unroll
    for (int i = t; i < 2304; i += 1024) ldsB4[i] = ws4[i];

    int wave = t >> 6, lane = t & 63, mrow = lane & 15, quad = lane >> 4;
    int px_l = wave * 16 + mrow;
    int remp = rem0 + px_l;
    int yp = remp >> 7, xp = remp & 127;
    const ushort_t* xb = xnb + (size_t)b * HW * CIN + quad * 8;

    // preload all 9 taps (loads all independent)
    uint4 af0[9], af1[9];
#pragma unroll
    for (int kk = 0; kk < 9; ++kk) {
        int yy = yp + kk / 3 - 1;
        int xq = xp + kk % 3 - 1;
        bool ok = (yy >= 0) && (yy < H_) && (xq >= 0) && (xq < W_);
        const ushort_t* src = xb + (size_t)(yy * W_ + xq) * CIN;
        af0[kk] = ok ? *(const uint4*)src        : make_uint4(0, 0, 0, 0);
        af1[kk] = ok ? *(const uint4*)(src + 32) : make_uint4(0, 0, 0, 0);
    }
    __syncthreads();

    f32x4 acc[2];
    acc[0] = (f32x4){0.f, 0.f, 0.f, 0.f};
    acc[1] = (f32x4){0.f, 0.f, 0.f, 0.f};
    const ushort_t* ldsB = (const ushort_t*)ldsB4;
#pragma unroll
    for (int kk = 0; kk < 9; ++kk) {
#pragma unroll
        for (int half = 0; half < 2; ++half) {
            int ks = kk * 2 + half;
            U4B a; a.u = half ? af1[kk] : af0[kk];
#pragma unroll
            for (int n = 0; n < 2; ++n) {
                bf16x8 bf = *(const bf16x8*)(ldsB + ((ks * 2 + n) * 64 + lane) * 8);
                acc[n] = __builtin_amdgcn_mfma_f32_16x16x32_bf16(a.v, bf, acc[n], 0, 0, 0);
            }
        }
    }

    // epilogue
#pragma unroll
    for (int n = 0; n < 2; ++n) {
        int co2 = n * 16 + mrow;
        if (co2 >= 27) continue;
        float bs = bias[co2];
#pragma unroll
        for (int r = 0; r < 4; ++r) {
            int px = wave * 16 + quad * 4 + r;
            float v = acc[n][r] + bs;
            if (co2 < 18) {
                off2[((size_t)(b * 9 + (co2 >> 1)) * HW + rem0 + px) * 2 + (co2 & 1)] = v;
            } else {
                mask_ws[(size_t)(b * 9 + (co2 - 18)) * HW + rem0 + px] =
                    1.0f / (1.0f + __expf(-v));
            }
        }
    }
}

// ---------------------------------------------------------------------------
// deform_mfma helpers — HALF-TAP pipeline granularity, lookahead 2.
// compute_tap: addresses (element offsets) + mask-folded bilinear weights.
// issue_half: 4 corner loads of ONE 8-channel half (4 uint4 = 16 VGPR).
// consume_half: interp 4 words + pack + 8 MFMAs (setprio-wrapped).
// ---------------------------------------------------------------------------
__device__ __forceinline__ void compute_tap(int yp_t, int xp_t,
                                            float oy, float ox, float mk,
                                            int* ofs, float* wg) {
    float py  = (float)yp_t + oy;
    float pxf = (float)xp_t + ox;
    float y0f = floorf(py), x0f = floorf(pxf);
    int yi = (int)y0f, xi = (int)x0f;
    float wy1 = py - y0f, wx1 = pxf - x0f;
    float wy0 = 1.0f - wy1, wx0 = 1.0f - wx1;
    int ya  = min(max(yi, 0), H_ - 1);
    int yb  = min(max(yi + 1, 0), H_ - 1);
    int xa  = min(max(xi, 0), W_ - 1);
    int xb2 = min(max(xi + 1, 0), W_ - 1);
    bool vy0 = (yi >= 0) & (yi < H_);
    bool vy1 = (yi >= -1) & (yi < H_ - 1);
    bool vx0 = (xi >= 0) & (xi < W_);
    bool vx1 = (xi >= -1) & (xi < W_ - 1);
    float m0 = mk * wy0, m1 = mk * wy1;
    wg[0] = (vy0 & vx0) ? m0 * wx0 : 0.0f;
    wg[1] = (vy0 & vx1) ? m0 * wx1 : 0.0f;
    wg[2] = (vy1 & vx0) ? m1 * wx0 : 0.0f;
    wg[3] = (vy1 & vx1) ? m1 * wx1 : 0.0f;
    int ra = ya << 13, rb = yb << 13;   // y * W_ * CIN
    int ca = xa << 6,  cb_ = xb2 << 6;  // x * CIN
    ofs[0] = ra + ca;  ofs[1] = ra + cb_;
    ofs[2] = rb + ca;  ofs[3] = rb + cb_;
}

__device__ __forceinline__ void issue_half(const ushort_t* __restrict__ xb,
                                           const int* ofs, int hoff, uint4* cb) {
#pragma unroll
    for (int c = 0; c < 4; ++c)
        cb[c] = *(const uint4*)(xb + ofs[c] + hoff);
}

__device__ __forceinline__ void consume_half(int ks, const uint4* cb,
                                             const float* wg,
                                             const ushort_t* __restrict__ ldsB,
                                             int lane, f32x4* acc) {
    float2 v2[4];
#pragma unroll
    for (int j = 0; j < 4; ++j) v2[j] = make_float2(0.f, 0.f);
#pragma unroll
    for (int c = 0; c < 4; ++c) {
        float w = wg[c];
        unsigned int ww[4] = {cb[c].x, cb[c].y, cb[c].z, cb[c].w};
#pragma unroll
        for (int j = 0; j < 4; ++j) {
            v2[j].x = fmaf(w, lo_f(ww[j]), v2[j].x);
            v2[j].y = fmaf(w, hi_f(ww[j]), v2[j].y);
        }
    }
    U4B a;
    a.u = make_uint4(pack2(v2[0].x, v2[0].y), pack2(v2[1].x, v2[1].y),
                     pack2(v2[2].x, v2[2].y), pack2(v2[3].x, v2[3].y));
    const ushort_t* bbase = ldsB + ((size_t)(ks * 8) * 64 + lane) * 8;
    __builtin_amdgcn_s_setprio(1);
#pragma unroll
    for (int n = 0; n < 8; ++n) {
        bf16x8 bf = *(const bf16x8*)(bbase + n * 64 * 8);
        acc[n] = __builtin_amdgcn_mfma_f32_16x16x32_bf16(a.v, bf, acc[n], 0, 0, 0);
    }
    __builtin_amdgcn_s_setprio(0);
}

// ---------------------------------------------------------------------------
// deform_mfma: fused bilinear sampling + GEMM. 1024 thr / 256 px / 16 waves.
// XCD-chunked swizzle (XCD k == batch k -> 4MB working set, L2-resident
// gathers). Half-tap software pipeline with LOOKAHEAD 2 (ring of 3 corner
// buffers, 8 loads in flight): issue hs+2 -> sched_barrier(0) -> consume hs.
// Offsets/masks pipelined 2-deep (even/odd tap slots).
// ---------------------------------------------------------------------------
__global__ __launch_bounds__(1024, 4) void deform_mfma(
        const ushort_t* __restrict__ xnb,
        const float* __restrict__ off2,
        const float* __restrict__ mask_ws,
        const ushort_t* __restrict__ wTs,
        ushort_t* __restrict__ prebn,
        float* __restrict__ gstat) {
    __shared__ uint4 ldsB4[9216];    // 147,456 B
    __shared__ float red[256];

    int t    = threadIdx.x;
    int bid  = blockIdx.x;
    int sbid = (bid & 7) * 64 + (bid >> 3);   // 512 = 8 XCDs x 64, bijective
    int pix0 = sbid * 256;
    int b    = pix0 >> 14;
    int rem0 = pix0 & 16383;

    const uint4* ws4 = (const uint4*)wTs;
#pragma unroll
    for (int i = 0; i < 9; ++i) ldsB4[i * 1024 + t] = ws4[i * 1024 + t];
    if (t < 256) red[t] = 0.0f;

    int wave = t >> 6, lane = t & 63, mrow = lane & 15, quad = lane >> 4;
    int px_l = wave * 16 + mrow;
    int remp = rem0 + px_l;
    int yp = remp >> 7, xp = remp & 127;
    const ushort_t* xb = xnb + (size_t)b * HW * CIN + quad * 8;
    size_t obase = (size_t)b * 9 * HW + remp;

    // 2-slot (even/odd tap) offset+mask prefetch: taps 0 and 1 pre-barrier.
    float2 oE = *(const float2*)(off2 + obase * 2);
    float2 oO = *(const float2*)(off2 + (obase + HW) * 2);
    float mkE = mask_ws[obase];
    float mkO = mask_ws[obase + HW];
    __syncthreads();

    f32x4 acc[8];
#pragma unroll
    for (int n = 0; n < 8; ++n) acc[n] = (f32x4){0.f, 0.f, 0.f, 0.f};
    const ushort_t* ldsB = (const ushort_t*)ldsB4;

    // addr/weight slots by tap parity; 3-deep corner-buffer ring by hs%3
    int   ofs[2][4];
    float wg[2][4];
    uint4 cb[3][4];

    // prologue: tap0 addresses, issue hs=0 and hs=1; refill E slot with tap2
    compute_tap(yp - 1, xp - 1, oE.x, oE.y, mkE, ofs[0], wg[0]);
    issue_half(xb, ofs[0], 0,  cb[0]);
    issue_half(xb, ofs[0], 32, cb[1]);
    oE  = *(const float2*)(off2 + (obase + (size_t)2 * HW) * 2);
    mkE = mask_ws[obase + (size_t)2 * HW];
    __builtin_amdgcn_sched_barrier(0);

#pragma unroll
    for (int hs = 0; hs < 18; ++hs) {
        const int hs2 = hs + 2;
        if (hs2 < 18) {
            const int kk2 = hs2 >> 1;   // tap being issued
            const int s2  = hs2 % 3;    // ring slot being filled
            if ((hs2 & 1) == 0) {
                const int tp2 = kk2 & 1;
                float ooy = tp2 ? oO.x : oE.x;
                float oox = tp2 ? oO.y : oE.y;
                float omk = tp2 ? mkO  : mkE;
                compute_tap(yp + kk2 / 3 - 1, xp + kk2 % 3 - 1, ooy, oox, omk,
                            ofs[tp2], wg[tp2]);
                issue_half(xb, ofs[tp2], 0, cb[s2]);
                if (kk2 + 2 <= 8) {   // refill this parity slot with tap kk2+2
                    float2 o = *(const float2*)(off2 + (obase + (size_t)(kk2 + 2) * HW) * 2);
                    float  m = mask_ws[obase + (size_t)(kk2 + 2) * HW];
                    if (tp2) { oO = o; mkO = m; } else { oE = o; mkE = m; }
                }
            } else {
                issue_half(xb, ofs[kk2 & 1], 32, cb[s2]);
            }
        }
        __builtin_amdgcn_sched_barrier(0);
        consume_half(hs, cb[hs % 3], wg[(hs >> 1) & 1], ldsB, lane, acc);
    }

    // ---- epilogue: bf16 NHWC store + BN stats (shuffle-reduce) ----
#pragma unroll
    for (int n = 0; n < 8; ++n) {
        int co = n * 16 + mrow;
        float s = 0.f, ss = 0.f;
#pragma unroll
        for (int r = 0; r < 4; ++r) {
            int pg = pix0 + wave * 16 + quad * 4 + r;
            float v = acc[n][r];
            prebn[(size_t)pg * COUT + co] = f2us_bf(v);
            s += v;
            ss += v * v;
        }
        s  += __shfl_xor(s, 16, 64);
        s  += __shfl_xor(s, 32, 64);
        ss += __shfl_xor(ss, 16, 64);
        ss += __shfl_xor(ss, 32, 64);
        if (quad == 0) {
            atomicAdd(&red[co], s);
            atomicAdd(&red[128 + co], ss);
        }
    }
    __syncthreads();
    if (t < 256) atomicAdd(&gstat[(bid & 15) * 256 + t], red[t]);
}

// ---------------------------------------------------------------------------
// bn_apply_t: derive mean/rstd from gstat per block (cheap), then read pre-BN
// bf16 NHWC, normalize+ReLU, write f32 NCHW d_out via LDS transpose tile.
// ---------------------------------------------------------------------------
__global__ __launch_bounds__(256) void bn_apply_t(const ushort_t* __restrict__ prebn,
                                                  const float* __restrict__ gstat,
                                                  float* __restrict__ out) {
    __shared__ float tile[128 * 65];
    __shared__ float mvs[256];
    int t = threadIdx.x;
    if (t < 128) {
        float s = 0.f, ss = 0.f;
#pragma unroll
        for (int part = 0; part < 16; ++part) {
            s  += gstat[part * 256 + t];
            ss += gstat[part * 256 + 128 + t];
        }
        const float invN = 1.0f / (float)NPIX;
        float mean = s * invN;
        float var  = ss * invN - mean * mean;
        if (!isfinite(mean)) mean = 0.0f;
        float r = rsqrtf(fmaxf(var, 0.0f) + 1e-5f);
        if (!isfinite(r)) r = 1.0f;
        mvs[t]       = mean;
        mvs[128 + t] = r;
    }
    __syncthreads();
    int pix0 = blockIdx.x * 64;
    int b    = pix0 >> 14;
    int rem0 = pix0 & 16383;
    const ushort_t* src = prebn + (size_t)pix0 * COUT;
#pragma unroll
    for (int r = 0; r < 32; ++r) {
        int i = r * 256 + t;
        int p = i >> 7, c = i & 127;
        float v = us2f(src[i]);
        v = fmaxf((v - mvs[c]) * mvs[128 + c], 0.0f);
        tile[c * 65 + p] = v;
    }
    __syncthreads();
#pragma unroll
    for (int r = 0; r < 32; ++r) {
        int i = r * 256 + t;
        int c2 = i >> 6, p2 = i & 63;
        out[(size_t)(b * COUT + c2) * HW + rem0 + p2] = tile[c2 * 65 + p2];
    }
}

// ---------------------------------------------------------------------------
extern "C" void kernel_launch(void* const* d_in, const int* in_sizes, int n_in,
                              void* d_out, int out_size, void* d_ws, size_t ws_size,
                              hipStream_t stream) {
    (void)in_sizes; (void)n_in; (void)out_size; (void)ws_size;
    const void* x     = d_in[0];
    const void* offw  = d_in[1];
    const void* offb  = d_in[2];
    const void* maskw = d_in[3];
    const void* maskb = d_in[4];
    const void* convw = d_in[5];

    float* ws       = (float*)d_ws;
    float* off2     = ws;                      // 2,359,296 f32 (y,x interleaved)
    float* mask_ws  = off2 + 2359296;          // 1,179,648 f32
    float* bias     = mask_ws + 1179648;       //        32 f32
    float* gstat    = bias + 32;               //     4,096 f32
    float* flag     = gstat + 4096;            //        16 f32
    ushort_t* wTs   = (ushort_t*)(flag + 16);  //    73,728 bf16 (frag-linear)
    ushort_t* wcats = wTs + 73728;             //    18,432 bf16 (frag-linear)
    ushort_t* xnb   = wcats + 18432;           // 8,388,608 bf16 (NHWC x)
    ushort_t* prebn = xnb + 8388608;           // 16,777,216 bf16 (NHWC pre-BN)
    float* out      = (float*)d_out;

    detect_zero<<<1, 256, 0, stream>>>((const uint4*)x, flag, gstat);
    prep_weights<<<361, 256, 0, stream>>>(offw, offb, maskw, maskb, convw, flag, wTs, wcats, bias);
    transpose_x<<<2048, 256, 0, stream>>>(x, flag, xnb);
    conv_mfma<<<512, 1024, 0, stream>>>(xnb, wcats, bias, off2, mask_ws);
    deform_mfma<<<512, 1024, 0, stream>>>(xnb, off2, mask_ws, wTs, prebn, gstat);
    bn_apply_t<<<2048, 256, 0, stream>>>(prebn, gstat, out);
}